// Round 6
// baseline (44.670 us; speedup 1.0000x reference)
//
#include <hip/hip_runtime.h>
#include <hip/hip_bf16.h>

// SHConv via bf16 MFMA: out[b,o,n] = sum_i x[b,i,n] * W_{l(n)}[i,o]
// x: (32,64,6561) f32, weight: (64,64,17,1) f32, out: (32,64,6561) f32
//
// R5 design: ALL global traffic in 256B-contiguous per-instruction segments.
// Block = (l, 64-position group, batch), 256 thr = 4 waves, LDS-decoupled:
//   stage:  lane = position -> x[ch][n0+lane] dword loads (256B contiguous),
//           into LDS xs[pos][ch] (pitch 66 dw -> 2-way banks = free)
//   mfma:   wave w = 16-pos chunk; B-frag from LDS (float2), A-frag + D layout
//           bit-identical to the verified R3/R4 kernel
//   store:  acc -> LDS os[o][pos] -> cooperative out[o][n0+lane] dword stores
//           (256B contiguous), predicated on pos < P.

#define NTOT 6561
#define NL   81
#define CH   64
#define NSLOT64 147                      // sum over l of ceil((2l+1)/64)
#define WTB_BYTES (NL * CH * CH * 2)     // 663552

typedef __attribute__((ext_vector_type(8))) short bf16x8;
typedef __attribute__((ext_vector_type(4))) float f32x4;

// ---- Kernel A: bf16 interpolated weight table, wtb[l][o][i] (i contiguous) ----
__global__ __launch_bounds__(256) void interp_bf16(const float* __restrict__ w,
                                                   __hip_bfloat16* __restrict__ wtb) {
  int idx = blockIdx.x * 256 + threadIdx.x;   // 1296*256 = 331776 exact
  int l = idx >> 12;
  int o = (idx >> 6) & 63;
  int i = idx & 63;
  int cp; float f;
  if (l < 75) { cp = l / 5; f = (float)(l - cp * 5) * 0.2f; }
  else        { cp = 15;    f = (float)(l - 75) * 0.2f; }
  const float* wp = w + (size_t)(i * 64 + o) * 17 + cp;   // weight[i][o][cp]
  float v = (1.0f - f) * wp[0] + f * wp[1];
  wtb[(size_t)l * 4096 + o * 64 + i] = __float2bfloat16(v);
}

// ---- Kernel B: grid (147, 32), block 256 = 4 waves ----
__global__ __launch_bounds__(256, 4) void shconv_mfma3(const float* __restrict__ x,
                                                       const __hip_bfloat16* __restrict__ wtb,
                                                       float* __restrict__ out) {
  __shared__ float xs[64][66];   // [pos][ch], pitch 66 dw: stage writes 2-way
  __shared__ float os[64][66];   // [o][pos],  pitch 66 dw: all phases <=2-way

  const int s = blockIdx.x;
  const int b = blockIdx.y;
  int l, c;
  if (s < 32)      { l = s;                  c = 0; }
  else if (s < 96) { l = 32 + ((s - 32) >> 1); c = (s - 32) & 1; }
  else             { l = 64 + (s - 96) / 3;    c = (s - 96) % 3; }
  const int P  = 2 * l + 1;
  const int n0 = l * l + c * 64;
  const int Pc = min(64, P - c * 64);        // valid positions in this group

  const int tid  = threadIdx.x;
  const int wv   = tid >> 6;
  const int lane = tid & 63;

  // ---- stage: 64 x 256B-contiguous loads, transpose into LDS ----
  {
    int n = n0 + lane;
    if (n > NTOT - 1) n = NTOT - 1;          // clamp: stays in-array, discarded later
    const float* xb = x + (size_t)b * CH * NTOT + n;
#pragma unroll
    for (int r = 0; r < 16; ++r) {
      const int ch = r * 4 + wv;
      xs[lane][ch] = xb[(size_t)ch * NTOT];
    }
  }
  __syncthreads();

  // ---- MFMA: wave w owns positions [w*16, w*16+16) of the group ----
  const int m   = lane & 15;
  const int kg  = lane >> 4;
  const int pc0 = wv * 16;
  if (pc0 < Pc) {
    const int p = pc0 + m;                   // local position (B col)

    bf16x8 bf[2];
#pragma unroll
    for (int ks = 0; ks < 2; ++ks) {
      const int i0 = ks * 32 + kg * 8;
#pragma unroll
      for (int u = 0; u < 4; ++u) {
        float2 v = *(const float2*)&xs[p][i0 + 2 * u];   // 8B aligned, 2-way banks
        __hip_bfloat16 h0 = __float2bfloat16(v.x);
        __hip_bfloat16 h1 = __float2bfloat16(v.y);
        bf[ks][2 * u]     = *reinterpret_cast<short*>(&h0);
        bf[ks][2 * u + 1] = *reinterpret_cast<short*>(&h1);
      }
    }

    const __hip_bfloat16* wl = wtb + (size_t)l * 4096;
    f32x4 acc[4];
#pragma unroll
    for (int t = 0; t < 4; ++t) acc[t] = (f32x4)(0.0f);

#pragma unroll
    for (int ks = 0; ks < 2; ++ks) {
#pragma unroll
      for (int t = 0; t < 4; ++t) {
        const int o  = t * 16 + m;
        const int i0 = ks * 32 + kg * 8;
        bf16x8 afrag = *reinterpret_cast<const bf16x8*>(wl + (size_t)o * 64 + i0);
        acc[t] = __builtin_amdgcn_mfma_f32_16x16x32_bf16(afrag, bf[ks], acc[t], 0, 0, 0);
      }
    }

    // D layout (verified): col = m, row = kg*4 + rg within each 16-row tile
#pragma unroll
    for (int t = 0; t < 4; ++t)
#pragma unroll
      for (int rg = 0; rg < 4; ++rg)
        os[t * 16 + kg * 4 + rg][pc0 + m] = acc[t][rg];
  }
  __syncthreads();

  // ---- store: 64 x 256B-contiguous stores, predicated on valid positions ----
  if (lane < Pc) {
    float* ob = out + (size_t)b * CH * NTOT + n0 + lane;
#pragma unroll
    for (int r = 0; r < 16; ++r) {
      const int o = r * 4 + wv;
      ob[(size_t)o * NTOT] = os[o][lane];
    }
  }
}

// ---- Fallback (no workspace): R2's passing fp32 LDS kernel ----
__global__ __launch_bounds__(192) void shconv_fallback(const float* __restrict__ x,
                                                       const float* __restrict__ w,
                                                       float* __restrict__ out) {
  __shared__ float wl[2][64][64];
  const int l1 = blockIdx.x;
  const int l2 = 80 - l1;
  const int P1 = 2 * l1 + 1;
  const int P2 = (l1 == 40) ? 0 : 2 * l2 + 1;
  int cp1, cp2; float f1, f2;
  if (l1 < 75) { cp1 = l1 / 5; f1 = (float)(l1 - cp1 * 5) * 0.2f; }
  else         { cp1 = 15;     f1 = (float)(l1 - 75) * 0.2f; }
  if (l2 < 75) { cp2 = l2 / 5; f2 = (float)(l2 - cp2 * 5) * 0.2f; }
  else         { cp2 = 15;     f2 = (float)(l2 - 75) * 0.2f; }
  const int tid = threadIdx.x;
  for (int e = tid; e < 8192; e += 192) {
    int sel = e >> 12, rr = e & 4095, i = rr >> 6, o = rr & 63;
    int cp = sel ? cp2 : cp1;
    float f = sel ? f2 : f1;
    const float* wp = w + (size_t)(i * 64 + o) * 17 + cp;
    wl[sel][i][o] = (1.0f - f) * wp[0] + f * wp[1];
  }
  __syncthreads();
  const int Ptot = P1 + P2;
  if (tid >= Ptot) return;
  int sel, l, p;
  if (tid < P1) { sel = 0; l = l1; p = tid; }
  else          { sel = 1; l = l2; p = tid - P1; }
  const size_t nidx = (size_t)(l * l) + p;
  const int b0 = blockIdx.y, b1 = b0 + 16;
  const float* x0 = x + (size_t)b0 * CH * NTOT + nidx;
  const float* x1 = x + (size_t)b1 * CH * NTOT + nidx;
  float acc0[64], acc1[64];
#pragma unroll
  for (int o = 0; o < 64; ++o) { acc0[o] = 0.f; acc1[o] = 0.f; }
  const float* wbase = &wl[sel][0][0];
#pragma unroll 4
  for (int i = 0; i < 64; ++i) {
    float xv0 = x0[(size_t)i * NTOT];
    float xv1 = x1[(size_t)i * NTOT];
    const float* wr = wbase + i * 64;
#pragma unroll
    for (int o = 0; o < 64; o += 4) {
      float4 wv = *(const float4*)(wr + o);
      acc0[o]     = fmaf(xv0, wv.x, acc0[o]);
      acc0[o + 1] = fmaf(xv0, wv.y, acc0[o + 1]);
      acc0[o + 2] = fmaf(xv0, wv.z, acc0[o + 2]);
      acc0[o + 3] = fmaf(xv0, wv.w, acc0[o + 3]);
      acc1[o]     = fmaf(xv1, wv.x, acc1[o]);
      acc1[o + 1] = fmaf(xv1, wv.y, acc1[o + 1]);
      acc1[o + 2] = fmaf(xv1, wv.z, acc1[o + 2]);
      acc1[o + 3] = fmaf(xv1, wv.w, acc1[o + 3]);
    }
  }
  float* o0 = out + (size_t)b0 * CH * NTOT + nidx;
  float* o1 = out + (size_t)b1 * CH * NTOT + nidx;
#pragma unroll
  for (int o = 0; o < 64; ++o) {
    o0[(size_t)o * NTOT] = acc0[o];
    o1[(size_t)o * NTOT] = acc1[o];
  }
}

extern "C" void kernel_launch(void* const* d_in, const int* in_sizes, int n_in,
                              void* d_out, int out_size, void* d_ws, size_t ws_size,
                              hipStream_t stream) {
  const float* x = (const float*)d_in[0];
  const float* w = (const float*)d_in[1];
  float* out = (float*)d_out;

  if (ws_size >= (size_t)WTB_BYTES && d_ws != nullptr) {
    __hip_bfloat16* wtb = (__hip_bfloat16*)d_ws;
    hipLaunchKernelGGL(interp_bf16, dim3(1296), dim3(256), 0, stream, w, wtb);
    hipLaunchKernelGGL(shconv_mfma3, dim3(NSLOT64, 32), dim3(256), 0, stream, x, wtb, out);
  } else {
    hipLaunchKernelGGL(shconv_fallback, dim3(41, 16), dim3(192), 0, stream, x, w, out);
  }
}